// Round 2
// baseline (2382.488 us; speedup 1.0000x reference)
//
#include <hip/hip_runtime.h>
#include <hip/hip_bf16.h>

// Problem constants (B,S,U,H,D) = (4,1024,1024,16,64)
constexpr int Bc = 4;
constexpr int Sc = 1024;
constexpr int Uc = 1024;
constexpr int Hc = 16;
constexpr int Dc = 64;
constexpr int NTOK = Bc * Sc;   // 4096

typedef unsigned short u16;

static __device__ __forceinline__ float bf2f(u16 u) {
    return __uint_as_float(((unsigned)u) << 16);
}
static __device__ __forceinline__ u16 f2bf(float f) {
    __hip_bfloat16 h = __float2bfloat16(f);   // RTNE
    return *reinterpret_cast<u16*>(&h);
}

// ---------------------------------------------------------------------------
// Dtype sniffer: decide whether raw inputs are bf16 (flag=0) or fp32 (flag=1).
// Genuine bf16 ~N(0,0.02): exponent field of every uint16 is <= ~123.
// fp32 read as uint16 pairs: low halves are ~uniform garbage, ~49% have
// exponent field >= 130 (|x|>=8). Check 256 uint16s of `query`.
// ---------------------------------------------------------------------------
__global__ void sniff_kernel(const u16* __restrict__ q, int* __restrict__ flag) {
    if (threadIdx.x == 0 && blockIdx.x == 0) {
        int big = 0;
        for (int i = 0; i < 256; ++i) {
            const int e = (q[i] >> 7) & 0xFF;
            big += (e >= 130) ? 1 : 0;
        }
        *flag = (big >= 4) ? 1 : 0;
    }
}

// ---------------------------------------------------------------------------
// Tiled fp32 GEMM with bias: Y[M,N] = X[M,K] @ W[K,N] + bias[N]
// BM=BN=64, BK=16, 256 threads, 4x4 microtile per thread.
// X: raw input (dtype per flag) if xRaw, else bf16 (workspace).
// W, bias: always raw (dtype per flag).
// Y: d_out (dtype per flag) if yRaw, else bf16 (workspace).
// ---------------------------------------------------------------------------
__global__ __launch_bounds__(256) void gemm_bias_kernel(
    const void* __restrict__ X, const void* __restrict__ W,
    const void* __restrict__ B, void* __restrict__ Y,
    const int* __restrict__ flag, int xRaw, int yRaw,
    int M, int K, int N)
{
    constexpr int BM = 64, BN = 64, BK = 16;
    __shared__ float As[BK][BM];   // As[k][m]
    __shared__ float Bs[BK][BN];   // Bs[k][n]

    const bool f  = (*flag != 0);
    const bool xf = (xRaw != 0) && f;   // X is fp32
    const bool wf = f;                  // W/bias fp32
    const bool yf = (yRaw != 0) && f;   // Y is fp32

    const int tid = threadIdx.x;
    const int tx = tid & 15;
    const int ty = tid >> 4;
    const int rowBase = blockIdx.x * BM;
    const int colBase = blockIdx.y * BN;

    float acc[4][4] = {};

    for (int k0 = 0; k0 < K; k0 += BK) {
        // A tile: 64 rows x 16 cols
        {
            const int col = tid & 15;
            const int row0 = tid >> 4;
#pragma unroll
            for (int p = 0; p < 4; ++p) {
                const int row = row0 + p * 16;
                const size_t i = (size_t)(rowBase + row) * K + k0 + col;
                As[col][row] = xf ? ((const float*)X)[i] : bf2f(((const u16*)X)[i]);
            }
        }
        // B tile: 16 rows x 64 cols (coalesced)
        {
            const int col = tid & 63;
            const int row0 = tid >> 6;
#pragma unroll
            for (int p = 0; p < 4; ++p) {
                const int row = row0 + p * 4;
                const size_t i = (size_t)(k0 + row) * N + colBase + col;
                Bs[row][col] = wf ? ((const float*)W)[i] : bf2f(((const u16*)W)[i]);
            }
        }
        __syncthreads();

#pragma unroll
        for (int kk = 0; kk < BK; ++kk) {
            float a[4], b[4];
#pragma unroll
            for (int i = 0; i < 4; ++i) a[i] = As[kk][ty * 4 + i];
#pragma unroll
            for (int j = 0; j < 4; ++j) b[j] = Bs[kk][tx * 4 + j];
#pragma unroll
            for (int i = 0; i < 4; ++i)
#pragma unroll
                for (int j = 0; j < 4; ++j)
                    acc[i][j] += a[i] * b[j];
        }
        __syncthreads();
    }

#pragma unroll
    for (int i = 0; i < 4; ++i) {
        const int row = rowBase + ty * 4 + i;
#pragma unroll
        for (int j = 0; j < 4; ++j) {
            const int col = colBase + tx * 4 + j;
            const float bv = wf ? ((const float*)B)[col] : bf2f(((const u16*)B)[col]);
            const float v = acc[i][j] + bv;
            const size_t o = (size_t)row * N + col;
            if (yf) ((float*)Y)[o] = v;
            else    ((u16*)Y)[o] = f2bf(v);
        }
    }
}

// ---------------------------------------------------------------------------
// Flash-style causal attention over bf16 q/k/v stored (B,S,H,D) as (B,S,U).
// One block = 64 queries for one (b,h). 4 threads per query row; thread `sub`
// owns key-chunk and O-dim-chunk [sub*16, sub*16+16).
// Writes ctx (bf16) IN PLACE over the q workspace: each block reads only its
// own q slice (once, at start) and writes only that same slice (at end).
// ---------------------------------------------------------------------------
__global__ __launch_bounds__(256) void attn_kernel(
    u16* __restrict__ qw, const u16* __restrict__ kw, const u16* __restrict__ vw)
{
    constexpr int BQ = 64, BKV = 64;
    __shared__ float Qs[BQ][Dc + 1];
    __shared__ float Ks[BKV][Dc + 1];
    __shared__ float Vs[BKV][Dc + 1];
    __shared__ float Ps[BQ][BKV + 1];

    const int tid = threadIdx.x;
    const int qlocal = tid >> 2;   // 0..63
    const int sub = tid & 3;       // 0..3
    const int qtile = blockIdx.x;
    const int bh = blockIdx.y;
    const int b = bh / Hc, h = bh % Hc;
    const int qb = qtile * BQ;
    const float scale = 0.125f;    // 1/sqrt(64)

    const u16* qbase = qw + (size_t)b * Sc * Uc + (size_t)h * Dc;
    const u16* kbase = kw + (size_t)b * Sc * Uc + (size_t)h * Dc;
    const u16* vbase = vw + (size_t)b * Sc * Uc + (size_t)h * Dc;

    // Load Q tile (64 x 64 bf16) via ushort4 (4 elems / 8 B)
    for (int idx = tid; idx < BQ * (Dc / 4); idx += 256) {
        const int r = idx >> 4;
        const int c = (idx & 15) * 4;
        const ushort4 u = *(const ushort4*)(qbase + (size_t)(qb + r) * Uc + c);
        Qs[r][c + 0] = bf2f(u.x); Qs[r][c + 1] = bf2f(u.y);
        Qs[r][c + 2] = bf2f(u.z); Qs[r][c + 3] = bf2f(u.w);
    }

    float O[16];
#pragma unroll
    for (int d = 0; d < 16; ++d) O[d] = 0.f;
    float m_run = -1e30f, l_run = 0.f;

    const int ntiles = qtile + 1;   // causal
    for (int t = 0; t < ntiles; ++t) {
        const int kb = t * BKV;
        __syncthreads();   // prev PV done (and Q writes done at t=0)
        for (int idx = tid; idx < BKV * (Dc / 4); idx += 256) {
            const int r = idx >> 4;
            const int c = (idx & 15) * 4;
            const ushort4 uk = *(const ushort4*)(kbase + (size_t)(kb + r) * Uc + c);
            Ks[r][c + 0] = bf2f(uk.x); Ks[r][c + 1] = bf2f(uk.y);
            Ks[r][c + 2] = bf2f(uk.z); Ks[r][c + 3] = bf2f(uk.w);
            const ushort4 uv = *(const ushort4*)(vbase + (size_t)(kb + r) * Uc + c);
            Vs[r][c + 0] = bf2f(uv.x); Vs[r][c + 1] = bf2f(uv.y);
            Vs[r][c + 2] = bf2f(uv.z); Vs[r][c + 3] = bf2f(uv.w);
        }
        __syncthreads();

        // Scores for this thread's 16 keys
        float s[16];
#pragma unroll
        for (int jj = 0; jj < 16; ++jj) {
            const int kj = sub * 16 + jj;
            float acc = 0.f;
#pragma unroll
            for (int dd = 0; dd < Dc; ++dd)
                acc += Qs[qlocal][dd] * Ks[kj][dd];
            acc *= scale;
            if (kb + kj > qb + qlocal) acc = -1e30f;   // causal mask
            s[jj] = acc;
        }

        // Row max across the 4 sub-threads (contiguous lanes)
        float mloc = s[0];
#pragma unroll
        for (int jj = 1; jj < 16; ++jj) mloc = fmaxf(mloc, s[jj]);
        mloc = fmaxf(mloc, __shfl_xor(mloc, 1));
        mloc = fmaxf(mloc, __shfl_xor(mloc, 2));
        const float m_new = fmaxf(m_run, mloc);
        const float alpha = __expf(m_run - m_new);

        float lloc = 0.f;
#pragma unroll
        for (int jj = 0; jj < 16; ++jj) {
            const float p = __expf(s[jj] - m_new);
            Ps[qlocal][sub * 16 + jj] = p;
            lloc += p;
        }
        lloc += __shfl_xor(lloc, 1);
        lloc += __shfl_xor(lloc, 2);
        l_run = l_run * alpha + lloc;
        m_run = m_new;
#pragma unroll
        for (int d = 0; d < 16; ++d) O[d] *= alpha;
        __syncthreads();   // Ps visible

#pragma unroll 4
        for (int kj2 = 0; kj2 < BKV; ++kj2) {
            const float p = Ps[qlocal][kj2];
#pragma unroll
            for (int d = 0; d < 16; ++d)
                O[d] += p * Vs[kj2][sub * 16 + d];
        }
    }

    const float inv = 1.f / l_run;
    u16* obase = qw + (size_t)(b * Sc + qb + qlocal) * Uc + h * Dc + sub * 16;
#pragma unroll
    for (int d = 0; d < 16; ++d) obase[d] = f2bf(O[d] * inv);
}

// ---------------------------------------------------------------------------
extern "C" void kernel_launch(void* const* d_in, const int* in_sizes, int n_in,
                              void* d_out, int out_size, void* d_ws, size_t ws_size,
                              hipStream_t stream)
{
    const void* query = d_in[0];
    const void* key   = d_in[1];
    const void* value = d_in[2];
    // d_in[3] = mask: exactly tril(ones) -> handled as causal, not read
    const void* Wq = d_in[4];
    const void* bq = d_in[5];
    const void* Wk = d_in[6];
    const void* bk = d_in[7];
    const void* Wv = d_in[8];
    const void* bv = d_in[9];
    const void* Wo = d_in[10];
    const void* bo = d_in[11];

    // Workspace layout (bf16 intermediates): qw, kw, vw = 8 MB each -> 24 MB,
    // then a 4-byte dtype flag. ctx reuses qw in place.
    u16* qw = (u16*)d_ws;
    u16* kw = qw + (size_t)NTOK * Uc;
    u16* vw = kw + (size_t)NTOK * Uc;
    int* flag = (int*)(vw + (size_t)NTOK * Uc);

    sniff_kernel<<<1, 64, 0, stream>>>((const u16*)query, flag);

    const dim3 ggemm(NTOK / 64, Uc / 64);   // 64 x 16 blocks
    gemm_bias_kernel<<<ggemm, 256, 0, stream>>>(query, Wq, bq, qw, flag, 1, 0, NTOK, Uc, Uc);
    gemm_bias_kernel<<<ggemm, 256, 0, stream>>>(key,   Wk, bk, kw, flag, 1, 0, NTOK, Uc, Uc);
    gemm_bias_kernel<<<ggemm, 256, 0, stream>>>(value, Wv, bv, vw, flag, 1, 0, NTOK, Uc, Uc);

    attn_kernel<<<dim3(Sc / 64, Bc * Hc), 256, 0, stream>>>(qw, kw, vw);

    // ctx (in qw) @ Wo + bo -> out (dtype per flag)
    gemm_bias_kernel<<<ggemm, 256, 0, stream>>>(qw, Wo, bo, d_out, flag, 0, 1, NTOK, Uc, Uc);
}

// Round 3
// 398.599 us; speedup vs baseline: 5.9772x; 5.9772x over previous
//
#include <hip/hip_runtime.h>
#include <hip/hip_bf16.h>

// (B,S,U,H,D) = (4,1024,1024,16,64); NTOK = 4096
typedef unsigned short u16;
typedef __attribute__((ext_vector_type(8))) short bf16x8;
typedef __attribute__((ext_vector_type(4))) float f32x4;

static __device__ __forceinline__ float bf2f(u16 u) {
    return __uint_as_float(((unsigned)u) << 16);
}
static __device__ __forceinline__ u16 f2bf(float f) {
    __hip_bfloat16 h = __float2bfloat16(f);   // RTNE
    return *reinterpret_cast<u16*>(&h);
}

// async global->LDS, 16 B per lane. LDS dest must be wave-uniform base + lane*16.
static __device__ __forceinline__ void g2lds16(const void* g, void* l) {
    __builtin_amdgcn_global_load_lds(
        (const __attribute__((address_space(1))) unsigned int*)g,
        (__attribute__((address_space(3))) unsigned int*)l, 16, 0, 0);
}

static __device__ __forceinline__ f32x4 mfma16(bf16x8 a, bf16x8 b, f32x4 c) {
    return __builtin_amdgcn_mfma_f32_16x16x32_bf16(a, b, c, 0, 0, 0);
}
static __device__ __forceinline__ bf16x8 ldfrag(const u16* base, int chunk) {
    return *(const bf16x8*)((const char*)base + (size_t)chunk * 16);
}

// ---------------------------------------------------------------------------
// Dtype sniffer (unchanged from R2 — R1's failure cause is still ambiguous,
// keep dual-dtype handling). flag=1 -> inputs are fp32, flag=0 -> bf16.
// ---------------------------------------------------------------------------
__global__ void sniff_kernel(const u16* __restrict__ q, int* __restrict__ flag) {
    if (threadIdx.x == 0 && blockIdx.x == 0) {
        int big = 0;
        for (int i = 0; i < 256; ++i) {
            const int e = (q[i] >> 7) & 0xFF;
            big += (e >= 130) ? 1 : 0;
        }
        *flag = (big >= 4) ? 1 : 0;
    }
}

// ---------------------------------------------------------------------------
// 64x64 transpose: dst[n][k] = bf16(src[k][n]). 1024x1024 matrices.
// blockIdx.z offsets both by z*1024*1024 elements (per-batch V transpose).
// ---------------------------------------------------------------------------
__global__ __launch_bounds__(256) void transpose64(
    const void* __restrict__ src, u16* __restrict__ dst,
    const int* __restrict__ flag, int xRaw)
{
    __shared__ u16 Ts[64][72];
    const int tid = threadIdx.x;
    const int r0 = blockIdx.x * 64;
    const int c0 = blockIdx.y * 64;
    const size_t zoff = (size_t)blockIdx.z * 1024 * 1024;
    const bool f = xRaw && (*flag != 0);
#pragma unroll
    for (int i = 0; i < 4; ++i) {
        const int idx = tid + i * 256;
        const int r = idx >> 4, c4 = (idx & 15) * 4;
        if (f) {
            const float4 v = *(const float4*)((const float*)src + zoff + (size_t)(r0 + r) * 1024 + c0 + c4);
            Ts[r][c4 + 0] = f2bf(v.x); Ts[r][c4 + 1] = f2bf(v.y);
            Ts[r][c4 + 2] = f2bf(v.z); Ts[r][c4 + 3] = f2bf(v.w);
        } else {
            const ushort4 v = *(const ushort4*)((const u16*)src + zoff + (size_t)(r0 + r) * 1024 + c0 + c4);
            Ts[r][c4 + 0] = v.x; Ts[r][c4 + 1] = v.y;
            Ts[r][c4 + 2] = v.z; Ts[r][c4 + 3] = v.w;
        }
    }
    __syncthreads();
#pragma unroll
    for (int i = 0; i < 4; ++i) {
        const int idx = tid + i * 256;
        const int r = idx >> 4, c4 = (idx & 15) * 4;
        ushort4 o;
        o.x = Ts[c4 + 0][r]; o.y = Ts[c4 + 1][r];
        o.z = Ts[c4 + 2][r]; o.w = Ts[c4 + 3][r];
        *(ushort4*)(dst + zoff + (size_t)(c0 + r) * 1024 + r0 + c4) = o;
    }
}

// ---------------------------------------------------------------------------
// MFMA GEMM: Y[4096,1024] = X[4096,1024] @ Wt^T + bias,  Wt is [n][k] bf16.
// BM=128, BN=64, BK=32; 256 thr = 4 waves, wave subtile 64x32 (4x2 frags).
// LDS chunk-swizzle ell(r,kc) = (r>>3)*Cc*8 + kc*8 + (r&7)  (Cc=4 chunks/row)
// -> frag ds_read_b128 lands 2-way on banks (free), staging stays lane-linear.
// A staged via VGPR (handles fp32-vs-bf16 flag); B via global_load_lds(16B).
// ---------------------------------------------------------------------------
__global__ __launch_bounds__(256) void gemm_mfma(
    const void* __restrict__ X, const u16* __restrict__ Wt,
    const void* __restrict__ Bias, void* __restrict__ Y,
    const int* __restrict__ flag, int xRaw, int yRaw)
{
    __shared__ __align__(16) u16 As[128 * 32];
    __shared__ __align__(16) u16 Bs[64 * 32];
    const bool f  = (*flag != 0);
    const bool xf = xRaw && f;
    const bool yf = yRaw && f;
    const int tid = threadIdx.x;
    const int lane = tid & 63, w = tid >> 6;
    const int quad = lane >> 4, l16 = lane & 15;
    const int wm = (w & 1) * 64, wn = (w >> 1) * 32;
    const int rowBase = blockIdx.x * 128, colBase = blockIdx.y * 64;

    f32x4 acc[4][2];
#pragma unroll
    for (int i = 0; i < 4; ++i)
#pragma unroll
        for (int j = 0; j < 2; ++j)
            acc[i][j] = f32x4{0.f, 0.f, 0.f, 0.f};

    for (int k0 = 0; k0 < 1024; k0 += 32) {
        __syncthreads();
        // B tile: 64 rows(n) x 4 chunks = 256 chunks, one per thread
        {
            const int l = tid;
            const int r = ((l >> 5) << 3) | (l & 7);
            const int kc = (l >> 3) & 3;
            g2lds16(Wt + (size_t)(colBase + r) * 1024 + k0 + kc * 8,
                    (char*)Bs + (size_t)l * 16);
        }
        // A tile: 128 rows(m) x 4 chunks = 512 chunks, two per thread
#pragma unroll
        for (int c = 0; c < 2; ++c) {
            const int l = c * 256 + tid;
            const int r = ((l >> 5) << 3) | (l & 7);
            const int kc = (l >> 3) & 3;
            int4 v;
            if (xf) {
                const float* p = (const float*)X + (size_t)(rowBase + r) * 1024 + k0 + kc * 8;
                const float4 v0 = *(const float4*)p;
                const float4 v1 = *(const float4*)(p + 4);
                u16* pv = (u16*)&v;
                pv[0] = f2bf(v0.x); pv[1] = f2bf(v0.y); pv[2] = f2bf(v0.z); pv[3] = f2bf(v0.w);
                pv[4] = f2bf(v1.x); pv[5] = f2bf(v1.y); pv[6] = f2bf(v1.z); pv[7] = f2bf(v1.w);
            } else {
                v = *(const int4*)((const u16*)X + (size_t)(rowBase + r) * 1024 + k0 + kc * 8);
            }
            *(int4*)((char*)As + (size_t)l * 16) = v;
        }
        __syncthreads();

        bf16x8 a[4], b[2];
#pragma unroll
        for (int i = 0; i < 4; ++i) {
            const int r = wm + i * 16 + l16;
            a[i] = ldfrag(As, ((r >> 3) << 5) | (quad << 3) | (r & 7));
        }
#pragma unroll
        for (int j = 0; j < 2; ++j) {
            const int r = wn + j * 16 + l16;
            b[j] = ldfrag(Bs, ((r >> 3) << 5) | (quad << 3) | (r & 7));
        }
#pragma unroll
        for (int i = 0; i < 4; ++i)
#pragma unroll
            for (int j = 0; j < 2; ++j)
                acc[i][j] = mfma16(a[i], b[j], acc[i][j]);
    }

    // Epilogue: C[m = quad*4+reg][n = lane&15] per frag (verified m89 layout)
#pragma unroll
    for (int j = 0; j < 2; ++j) {
        const int col = colBase + wn + j * 16 + l16;
        const float bv = f ? ((const float*)Bias)[col] : bf2f(((const u16*)Bias)[col]);
#pragma unroll
        for (int i = 0; i < 4; ++i) {
#pragma unroll
            for (int reg = 0; reg < 4; ++reg) {
                const int row = rowBase + wm + i * 16 + quad * 4 + reg;
                const float val = acc[i][j][reg] + bv;
                const size_t o = (size_t)row * 1024 + col;
                if (yf) ((float*)Y)[o] = val;
                else    ((u16*)Y)[o] = f2bf(val);
            }
        }
    }
}

// ---------------------------------------------------------------------------
// Flash-attention, MFMA. One block = (qtile of 64 q, one (b,h)); 4 waves, each
// owns a 16-query strip. QK^T: A=Q[q][d], B=K[key][d] (both K-contiguous, LDS
// swizzled, Cc=8). P: C-layout -> bf16 -> per-wave LDS strip Ps[16][72] ->
// A-layout reads. PV: B = V^T[d][key] from vt. ctx written in-place over qw.
// ---------------------------------------------------------------------------
__global__ __launch_bounds__(256) void attn_mfma(
    u16* __restrict__ qw, const u16* __restrict__ kw, const u16* __restrict__ vt)
{
    __shared__ __align__(16) u16 Qs[64 * 64];
    __shared__ __align__(16) u16 Ks[64 * 64];
    __shared__ __align__(16) u16 Vs[64 * 64];
    __shared__ __align__(16) u16 Ps[4][16 * 72];

    const int tid = threadIdx.x;
    const int lane = tid & 63, w = tid >> 6;
    const int quad = lane >> 4, l16 = lane & 15;
    const int qtile = blockIdx.x, bh = blockIdx.y;
    const int b = bh >> 4, h = bh & 15;
    const int qb = qtile * 64;

    const u16* qg = qw + (size_t)(b * 1024 + qb) * 1024 + h * 64;
    const u16* kg0 = kw + (size_t)(b * 1024) * 1024 + h * 64;
    const u16* vg0 = vt + (size_t)(b * 1024 + h * 64) * 1024;

    // Stage Q once: 64 rows x 8 chunks = 512 chunks
#pragma unroll
    for (int c = 0; c < 2; ++c) {
        const int l = c * 256 + tid;
        const int r = ((l >> 6) << 3) | (l & 7);
        const int kc = (l >> 3) & 7;
        g2lds16(qg + (size_t)r * 1024 + kc * 8, (char*)Qs + (size_t)l * 16);
    }

    f32x4 O[4];
#pragma unroll
    for (int j = 0; j < 4; ++j) O[j] = f32x4{0.f, 0.f, 0.f, 0.f};
    float m_run[4] = {-1e30f, -1e30f, -1e30f, -1e30f};
    float l_run[4] = {0.f, 0.f, 0.f, 0.f};

    u16* psw = Ps[w];

    for (int t = 0; t <= qtile; ++t) {
        const int kb = t * 64;
        __syncthreads();   // previous tile's LDS reads done (covers Q at t=0)
#pragma unroll
        for (int c = 0; c < 2; ++c) {
            const int l = c * 256 + tid;
            const int r = ((l >> 6) << 3) | (l & 7);
            const int kc = (l >> 3) & 7;
            g2lds16(kg0 + (size_t)(kb + r) * 1024 + kc * 8, (char*)Ks + (size_t)l * 16);
            g2lds16(vg0 + (size_t)r * 1024 + kb + kc * 8,   (char*)Vs + (size_t)l * 16);
        }
        __syncthreads();   // drains global_load_lds (vmcnt(0) before barrier)

        // ---- S = Q K^T (strip rows w*16..+15, 64 keys) ----
        bf16x8 aq[2];
#pragma unroll
        for (int kt = 0; kt < 2; ++kt) {
            const int r = w * 16 + l16;
            aq[kt] = ldfrag(Qs, ((r >> 3) << 6) | ((kt * 4 + quad) << 3) | (r & 7));
        }
        f32x4 s[4];
#pragma unroll
        for (int j = 0; j < 4; ++j) {
            const int r = j * 16 + l16;
            const bf16x8 b0 = ldfrag(Ks, ((r >> 3) << 6) | ((0 + quad) << 3) | (r & 7));
            const bf16x8 b1 = ldfrag(Ks, ((r >> 3) << 6) | ((4 + quad) << 3) | (r & 7));
            f32x4 z = f32x4{0.f, 0.f, 0.f, 0.f};
            z = mfma16(aq[0], b0, z);
            s[j] = mfma16(aq[1], b1, z);
        }

        // ---- scale + causal mask (only the diagonal tile needs masking) ----
        const int qrow0 = w * 16 + quad * 4;   // local query row of reg 0
#pragma unroll
        for (int j = 0; j < 4; ++j) {
            const int key = j * 16 + l16;
#pragma unroll
            for (int reg = 0; reg < 4; ++reg) {
                float v = s[j][reg] * 0.125f;
                if (t == qtile && key > qrow0 + reg) v = -1e30f;
                s[j][reg] = v;
            }
        }

        // ---- online softmax (per reg-row; butterfly over the 16-lane quad) --
        float alpha[4];
#pragma unroll
        for (int reg = 0; reg < 4; ++reg) {
            float mx = fmaxf(fmaxf(s[0][reg], s[1][reg]), fmaxf(s[2][reg], s[3][reg]));
#pragma unroll
            for (int d = 1; d < 16; d <<= 1)
                mx = fmaxf(mx, __shfl_xor(mx, d));
            const float m_new = fmaxf(m_run[reg], mx);
            alpha[reg] = __expf(m_run[reg] - m_new);
            float sm = 0.f;
#pragma unroll
            for (int j = 0; j < 4; ++j) {
                const float p = __expf(s[j][reg] - m_new);
                s[j][reg] = p;   // reuse s as P
                sm += p;
            }
#pragma unroll
            for (int d = 1; d < 16; d <<= 1)
                sm += __shfl_xor(sm, d);
            l_run[reg] = l_run[reg] * alpha[reg] + sm;
            m_run[reg] = m_new;
        }

        // ---- P -> per-wave LDS strip (C-layout -> A-layout round trip) ----
#pragma unroll
        for (int j = 0; j < 4; ++j)
#pragma unroll
            for (int reg = 0; reg < 4; ++reg)
                psw[(quad * 4 + reg) * 72 + j * 16 + l16] = f2bf(s[j][reg]);

#pragma unroll
        for (int j = 0; j < 4; ++j)
#pragma unroll
            for (int reg = 0; reg < 4; ++reg)
                O[j][reg] *= alpha[reg];

        // ---- O += P V  (A from Ps strip, B from V^T tile) ----
        bf16x8 ap[2];
#pragma unroll
        for (int kt = 0; kt < 2; ++kt)
            ap[kt] = *(const bf16x8*)((const char*)psw + (size_t)l16 * 144 + kt * 64 + quad * 16);
#pragma unroll
        for (int j = 0; j < 4; ++j) {
            const int r = j * 16 + l16;   // d row
            const bf16x8 b0 = ldfrag(Vs, ((r >> 3) << 6) | ((0 + quad) << 3) | (r & 7));
            const bf16x8 b1 = ldfrag(Vs, ((r >> 3) << 6) | ((4 + quad) << 3) | (r & 7));
            O[j] = mfma16(ap[0], b0, O[j]);
            O[j] = mfma16(ap[1], b1, O[j]);
        }
    }

    // ---- normalize + write ctx in place over qw (own (qtile,h) slice only) --
    u16* og = qw + (size_t)(b * 1024 + qb + w * 16 + quad * 4) * 1024 + h * 64;
#pragma unroll
    for (int reg = 0; reg < 4; ++reg) {
        const float inv = 1.f / l_run[reg];
#pragma unroll
        for (int j = 0; j < 4; ++j)
            og[(size_t)reg * 1024 + j * 16 + l16] = f2bf(O[j][reg] * inv);
    }
}

// ---------------------------------------------------------------------------
extern "C" void kernel_launch(void* const* d_in, const int* in_sizes, int n_in,
                              void* d_out, int out_size, void* d_ws, size_t ws_size,
                              hipStream_t stream)
{
    const void* query = d_in[0];
    const void* key   = d_in[1];
    const void* value = d_in[2];
    // d_in[3] = mask: exactly tril(ones) -> causal, not read
    const void* Wq = d_in[4];
    const void* bq = d_in[5];
    const void* Wk = d_in[6];
    const void* bk = d_in[7];
    const void* Wv = d_in[8];
    const void* bv = d_in[9];
    const void* Wo = d_in[10];
    const void* bo = d_in[11];

    // ws: qw 8MB | kw 8MB | vt 8MB | Wt_q,Wt_k,Wt_v 2MB each | vw 8MB | flag
    //     (vw is dead after transpose_v; its first 2MB is reused for Wo^T)
    u16* qw   = (u16*)d_ws;
    u16* kw   = qw + (size_t)4 * 1024 * 1024;
    u16* vt   = kw + (size_t)4 * 1024 * 1024;
    u16* wt_q = vt + (size_t)4 * 1024 * 1024;
    u16* wt_k = wt_q + (size_t)1024 * 1024;
    u16* wt_v = wt_k + (size_t)1024 * 1024;
    u16* vw   = wt_v + (size_t)1024 * 1024;
    u16* wt_o = vw;
    int* flag = (int*)(vw + (size_t)4 * 1024 * 1024);

    sniff_kernel<<<1, 64, 0, stream>>>((const u16*)query, flag);

    const dim3 tg(16, 16);
    transpose64<<<tg, 256, 0, stream>>>(Wq, wt_q, flag, 1);
    transpose64<<<tg, 256, 0, stream>>>(Wk, wt_k, flag, 1);
    transpose64<<<tg, 256, 0, stream>>>(Wv, wt_v, flag, 1);

    const dim3 gg(32, 16);   // (4096/128, 1024/64)
    gemm_mfma<<<gg, 256, 0, stream>>>(query, wt_q, bq, qw, flag, 1, 0);
    gemm_mfma<<<gg, 256, 0, stream>>>(key,   wt_k, bk, kw, flag, 1, 0);
    gemm_mfma<<<gg, 256, 0, stream>>>(value, wt_v, bv, vw, flag, 1, 0);

    transpose64<<<dim3(16, 16, 4), 256, 0, stream>>>(vw, vt, flag, 0);  // per-b V^T
    transpose64<<<tg, 256, 0, stream>>>(Wo, wt_o, flag, 1);             // vw now dead

    attn_mfma<<<dim3(16, 64), 256, 0, stream>>>(qw, kw, vt);

    gemm_mfma<<<gg, 256, 0, stream>>>(qw, wt_o, bo, d_out, flag, 0, 1);
}

// Round 4
// 298.794 us; speedup vs baseline: 7.9737x; 1.3340x over previous
//
#include <hip/hip_runtime.h>
#include <hip/hip_bf16.h>

// (B,S,U,H,D) = (4,1024,1024,16,64); NTOK = 4096
typedef unsigned short u16;
typedef __attribute__((ext_vector_type(8))) short bf16x8;
typedef __attribute__((ext_vector_type(4))) float f32x4;

static __device__ __forceinline__ float bf2f(u16 u) {
    return __uint_as_float(((unsigned)u) << 16);
}
static __device__ __forceinline__ u16 f2bf(float f) {
    __hip_bfloat16 h = __float2bfloat16(f);   // RTNE
    return *reinterpret_cast<u16*>(&h);
}
static __device__ __forceinline__ void g2lds16(const void* g, void* l) {
    __builtin_amdgcn_global_load_lds(
        (const __attribute__((address_space(1))) unsigned int*)g,
        (__attribute__((address_space(3))) unsigned int*)l, 16, 0, 0);
}
static __device__ __forceinline__ f32x4 mfma16(bf16x8 a, bf16x8 b, f32x4 c) {
    return __builtin_amdgcn_mfma_f32_16x16x32_bf16(a, b, c, 0, 0, 0);
}
static __device__ __forceinline__ bf16x8 ldfrag(const u16* base, int chunk) {
    return *(const bf16x8*)((const char*)base + (size_t)chunk * 16);
}
static __device__ __forceinline__ float fexp2(float x) {
    return __builtin_amdgcn_exp2f(x);   // v_exp_f32 (2^x), 1 instr
}

// ---------------------------------------------------------------------------
// Dtype sniffer (insurance; evidence says inputs are bf16 -> flag=0).
// 64 lanes each check one u16 of `query`; bf16 N(0,0.02) never has exponent
// field >= 130; fp32-as-u16 low halves do ~49% of the time.
// ---------------------------------------------------------------------------
__global__ void sniff_kernel(const u16* __restrict__ q, int* __restrict__ flag) {
    const int i = threadIdx.x;   // 64 threads
    const int e = (q[i] >> 7) & 0xFF;
    const unsigned long long m = __ballot(e >= 130);
    if (i == 0) *flag = (__popcll(m) >= 2) ? 1 : 0;
}

// ---------------------------------------------------------------------------
// Fused 4x transpose: dst_z[n][k] = bf16(src_z[k][n]), each 1024x1024.
// z = blockIdx.z selects the (src,dst) pair.
// ---------------------------------------------------------------------------
struct T4 { const void* src[4]; u16* dst[4]; };

__global__ __launch_bounds__(256) void transpose64(
    T4 ta, const int* __restrict__ flag, int xRaw)
{
    __shared__ u16 Ts[64][72];
    const void* src = ta.src[blockIdx.z];
    u16* dst = ta.dst[blockIdx.z];
    const int tid = threadIdx.x;
    const int r0 = blockIdx.x * 64;
    const int c0 = blockIdx.y * 64;
    const bool f = xRaw && (*flag != 0);
#pragma unroll
    for (int i = 0; i < 4; ++i) {
        const int idx = tid + i * 256;
        const int r = idx >> 4, c4 = (idx & 15) * 4;
        if (f) {
            const float4 v = *(const float4*)((const float*)src + (size_t)(r0 + r) * 1024 + c0 + c4);
            Ts[r][c4 + 0] = f2bf(v.x); Ts[r][c4 + 1] = f2bf(v.y);
            Ts[r][c4 + 2] = f2bf(v.z); Ts[r][c4 + 3] = f2bf(v.w);
        } else {
            const ushort4 v = *(const ushort4*)((const u16*)src + (size_t)(r0 + r) * 1024 + c0 + c4);
            Ts[r][c4 + 0] = v.x; Ts[r][c4 + 1] = v.y;
            Ts[r][c4 + 2] = v.z; Ts[r][c4 + 3] = v.w;
        }
    }
    __syncthreads();
#pragma unroll
    for (int i = 0; i < 4; ++i) {
        const int idx = tid + i * 256;
        const int r = idx >> 4, c4 = (idx & 15) * 4;
        ushort4 o;
        o.x = Ts[c4 + 0][r]; o.y = Ts[c4 + 1][r];
        o.z = Ts[c4 + 2][r]; o.w = Ts[c4 + 3][r];
        *(ushort4*)(dst + (size_t)(c0 + r) * 1024 + r0 + c4) = o;
    }
}

// ---------------------------------------------------------------------------
// MFMA GEMM (m97 structure): Y[4096,1024] = X @ Wt^T + bias, Wt is [n][k] bf16.
// BM=BN=128, BK=32; 256 thr = 4 waves in 2x2, wave subtile 64x64 (4x4 frags,
// 16 MFMA/iter). Both A and B staged via global_load_lds(16B). LDS chunk
// swizzle ell(r,kc)=(r>>3)*32 + kc*8 + (r&7) -> frag ds_read_b128 is 2-way
// bank-aliased (free, m136). z = blockIdx.z selects one of up to 3 GEMMs.
// ---------------------------------------------------------------------------
struct G1 { const void* X; const u16* Wt; const void* Bias; void* Y; };
struct G3 { G1 g[3]; };

__global__ __launch_bounds__(256) void gemm_mfma(
    G3 args, const int* __restrict__ flag, int xRaw, int yRaw)
{
    __shared__ __align__(16) u16 As[128 * 32];
    __shared__ __align__(16) u16 Bs[128 * 32];
    const G1 g = args.g[blockIdx.z];
    const bool f  = (*flag != 0);
    const bool xf = xRaw && f;
    const bool yf = yRaw && f;
    const int tid = threadIdx.x;
    const int lane = tid & 63, w = tid >> 6;
    const int quad = lane >> 4, l16 = lane & 15;
    const int wm = (w & 1) * 64, wn = (w >> 1) * 64;
    const int rowBase = blockIdx.x * 128, colBase = blockIdx.y * 128;

    f32x4 acc[4][4];
#pragma unroll
    for (int i = 0; i < 4; ++i)
#pragma unroll
        for (int j = 0; j < 4; ++j)
            acc[i][j] = f32x4{0.f, 0.f, 0.f, 0.f};

    for (int k0 = 0; k0 < 1024; k0 += 32) {
        __syncthreads();
        // B tile: 128 rows(n) x 4 chunks = 512 -> 2 per thread
#pragma unroll
        for (int c = 0; c < 2; ++c) {
            const int l = c * 256 + tid;
            const int r = ((l >> 5) << 3) | (l & 7);
            const int kc = (l >> 3) & 3;
            g2lds16(g.Wt + (size_t)(colBase + r) * 1024 + k0 + kc * 8,
                    (char*)Bs + (size_t)l * 16);
        }
        // A tile: 128 rows(m) x 4 chunks = 512 -> 2 per thread
        if (!xf) {
#pragma unroll
            for (int c = 0; c < 2; ++c) {
                const int l = c * 256 + tid;
                const int r = ((l >> 5) << 3) | (l & 7);
                const int kc = (l >> 3) & 3;
                g2lds16((const u16*)g.X + (size_t)(rowBase + r) * 1024 + k0 + kc * 8,
                        (char*)As + (size_t)l * 16);
            }
        } else {
#pragma unroll
            for (int c = 0; c < 2; ++c) {
                const int l = c * 256 + tid;
                const int r = ((l >> 5) << 3) | (l & 7);
                const int kc = (l >> 3) & 3;
                const float* p = (const float*)g.X + (size_t)(rowBase + r) * 1024 + k0 + kc * 8;
                const float4 v0 = *(const float4*)p;
                const float4 v1 = *(const float4*)(p + 4);
                int4 v;
                u16* pv = (u16*)&v;
                pv[0] = f2bf(v0.x); pv[1] = f2bf(v0.y); pv[2] = f2bf(v0.z); pv[3] = f2bf(v0.w);
                pv[4] = f2bf(v1.x); pv[5] = f2bf(v1.y); pv[6] = f2bf(v1.z); pv[7] = f2bf(v1.w);
                *(int4*)((char*)As + (size_t)l * 16) = v;
            }
        }
        __syncthreads();

        bf16x8 a[4], b[4];
#pragma unroll
        for (int i = 0; i < 4; ++i) {
            const int r = wm + i * 16 + l16;
            a[i] = ldfrag(As, ((r >> 3) << 5) | (quad << 3) | (r & 7));
        }
#pragma unroll
        for (int j = 0; j < 4; ++j) {
            const int r = wn + j * 16 + l16;
            b[j] = ldfrag(Bs, ((r >> 3) << 5) | (quad << 3) | (r & 7));
        }
#pragma unroll
        for (int i = 0; i < 4; ++i)
#pragma unroll
            for (int j = 0; j < 4; ++j)
                acc[i][j] = mfma16(a[i], b[j], acc[i][j]);
    }

    // Epilogue: C[m = quad*4+reg][n = lane&15] (verified m89 layout)
#pragma unroll
    for (int j = 0; j < 4; ++j) {
        const int col = colBase + wn + j * 16 + l16;
        const float bv = f ? ((const float*)g.Bias)[col] : bf2f(((const u16*)g.Bias)[col]);
#pragma unroll
        for (int i = 0; i < 4; ++i) {
#pragma unroll
            for (int reg = 0; reg < 4; ++reg) {
                const int row = rowBase + wm + i * 16 + quad * 4 + reg;
                const float val = acc[i][j][reg] + bv;
                const size_t o = (size_t)row * 1024 + col;
                if (yf) ((float*)g.Y)[o] = val;
                else    ((u16*)g.Y)[o] = f2bf(val);
            }
        }
    }
}

// ---------------------------------------------------------------------------
// Flash attention, paired q-tiles for uniform causal work.
// Block = (qp, bh): handles q-tiles qtA=qp and qtB=15-qp for one (b,h);
// total kv-tiles per block = (qtA+1)+(qtB+1) = 17 (uniform). 4 waves; wave w
// owns 16-query strip w of BOTH tiles, sharing each staged K/V tile.
// Softmax in base-2 (scale pre-multiplied by log2 e). ctx in-place over qw.
// ---------------------------------------------------------------------------
static __device__ __forceinline__ void attn_strip(
    const u16* __restrict__ Ks, const u16* __restrict__ Vs,
    u16* __restrict__ psw, const bf16x8* aq,
    float* m_run, float* l_run, f32x4* O,
    int w, int quad, int l16, bool diag)
{
    // ---- S = Q K^T (16 q x 64 keys) ----
    f32x4 s[4];
#pragma unroll
    for (int j = 0; j < 4; ++j) {
        const int r = j * 16 + l16;
        const bf16x8 b0 = ldfrag(Ks, ((r >> 3) << 6) | (quad << 3) | (r & 7));
        const bf16x8 b1 = ldfrag(Ks, ((r >> 3) << 6) | ((4 + quad) << 3) | (r & 7));
        f32x4 z = f32x4{0.f, 0.f, 0.f, 0.f};
        z = mfma16(aq[0], b0, z);
        s[j] = mfma16(aq[1], b1, z);
    }

    // ---- scale (base-2 domain) + causal mask on diagonal tile ----
    const float SC2 = 0.125f * 1.44269504089f;   // scale * log2(e)
    const int qrow0 = w * 16 + quad * 4;
#pragma unroll
    for (int j = 0; j < 4; ++j) {
        const int key = j * 16 + l16;
#pragma unroll
        for (int reg = 0; reg < 4; ++reg) {
            float v = s[j][reg] * SC2;
            if (diag && key > qrow0 + reg) v = -1e30f;
            s[j][reg] = v;
        }
    }

    // ---- online softmax, per reg-row, butterfly over 16-lane quad row ----
    float alpha[4];
#pragma unroll
    for (int reg = 0; reg < 4; ++reg) {
        float mx = fmaxf(fmaxf(s[0][reg], s[1][reg]), fmaxf(s[2][reg], s[3][reg]));
#pragma unroll
        for (int d = 1; d < 16; d <<= 1)
            mx = fmaxf(mx, __shfl_xor(mx, d));
        const float m_new = fmaxf(m_run[reg], mx);
        alpha[reg] = fexp2(m_run[reg] - m_new);
        float sm = 0.f;
#pragma unroll
        for (int j = 0; j < 4; ++j) {
            const float p = fexp2(s[j][reg] - m_new);
            s[j][reg] = p;
            sm += p;
        }
#pragma unroll
        for (int d = 1; d < 16; d <<= 1)
            sm += __shfl_xor(sm, d);
        l_run[reg] = l_run[reg] * alpha[reg] + sm;
        m_run[reg] = m_new;
    }

    // ---- P: C-layout -> per-wave LDS strip (A-layout source) ----
#pragma unroll
    for (int j = 0; j < 4; ++j)
#pragma unroll
        for (int reg = 0; reg < 4; ++reg)
            psw[(quad * 4 + reg) * 72 + j * 16 + l16] = f2bf(s[j][reg]);

#pragma unroll
    for (int j = 0; j < 4; ++j)
#pragma unroll
        for (int reg = 0; reg < 4; ++reg)
            O[j][reg] *= alpha[reg];

    // ---- O += P V (A from strip, B from V^T tile) ----
    bf16x8 ap[2];
#pragma unroll
    for (int kt = 0; kt < 2; ++kt)
        ap[kt] = *(const bf16x8*)((const char*)psw + (size_t)l16 * 144 + kt * 64 + quad * 16);
#pragma unroll
    for (int j = 0; j < 4; ++j) {
        const int r = j * 16 + l16;   // d row of V^T
        const bf16x8 b0 = ldfrag(Vs, ((r >> 3) << 6) | (quad << 3) | (r & 7));
        const bf16x8 b1 = ldfrag(Vs, ((r >> 3) << 6) | ((4 + quad) << 3) | (r & 7));
        O[j] = mfma16(ap[0], b0, O[j]);
        O[j] = mfma16(ap[1], b1, O[j]);
    }
}

__global__ __launch_bounds__(256) void attn_mfma(
    u16* __restrict__ qw, const u16* __restrict__ kw, const u16* __restrict__ vt)
{
    __shared__ __align__(16) u16 QA[64 * 64];
    __shared__ __align__(16) u16 QB[64 * 64];
    __shared__ __align__(16) u16 Ks[64 * 64];
    __shared__ __align__(16) u16 Vs[64 * 64];
    __shared__ __align__(16) u16 Ps[4][16 * 72];

    const int tid = threadIdx.x;
    const int lane = tid & 63, w = tid >> 6;
    const int quad = lane >> 4, l16 = lane & 15;
    const int qp = blockIdx.x, bh = blockIdx.y;
    const int b = bh >> 4, h = bh & 15;
    const int qtA = qp, qtB = 15 - qp;

    const u16* qgA = qw + (size_t)(b * 1024 + qtA * 64) * 1024 + h * 64;
    const u16* qgB = qw + (size_t)(b * 1024 + qtB * 64) * 1024 + h * 64;
    const u16* kg0 = kw + (size_t)(b * 1024) * 1024 + h * 64;
    const u16* vg0 = vt + (size_t)(b * 1024 + h * 64) * 1024;

    // Stage both Q tiles once (512 chunks each -> 2/thread each)
#pragma unroll
    for (int c = 0; c < 2; ++c) {
        const int l = c * 256 + tid;
        const int r = ((l >> 6) << 3) | (l & 7);
        const int kc = (l >> 3) & 7;
        g2lds16(qgA + (size_t)r * 1024 + kc * 8, (char*)QA + (size_t)l * 16);
        g2lds16(qgB + (size_t)r * 1024 + kc * 8, (char*)QB + (size_t)l * 16);
    }

    f32x4 OA[4], OB[4];
    float mA[4], lA[4], mB[4], lB[4];
#pragma unroll
    for (int j = 0; j < 4; ++j) {
        OA[j] = f32x4{0.f, 0.f, 0.f, 0.f};
        OB[j] = f32x4{0.f, 0.f, 0.f, 0.f};
        mA[j] = -1e30f; lA[j] = 0.f;
        mB[j] = -1e30f; lB[j] = 0.f;
    }
    bf16x8 aqA[2], aqB[2];
    u16* psw = Ps[w];

    for (int t = 0; t <= qtB; ++t) {
        const int kb = t * 64;
        __syncthreads();   // prior tile's LDS reads done
#pragma unroll
        for (int c = 0; c < 2; ++c) {
            const int l = c * 256 + tid;
            const int r = ((l >> 6) << 3) | (l & 7);
            const int kc = (l >> 3) & 7;
            g2lds16(kg0 + (size_t)(kb + r) * 1024 + kc * 8, (char*)Ks + (size_t)l * 16);
            g2lds16(vg0 + (size_t)r * 1024 + kb + kc * 8,   (char*)Vs + (size_t)l * 16);
        }
        __syncthreads();   // vmcnt(0) drain: K/V (and, at t=0, Q) resident

        if (t == 0) {
            const int r = w * 16 + l16;
#pragma unroll
            for (int kt = 0; kt < 2; ++kt) {
                aqA[kt] = ldfrag(QA, ((r >> 3) << 6) | ((kt * 4 + quad) << 3) | (r & 7));
                aqB[kt] = ldfrag(QB, ((r >> 3) << 6) | ((kt * 4 + quad) << 3) | (r & 7));
            }
        }

        attn_strip(Ks, Vs, psw, aqB, mB, lB, OB, w, quad, l16, t == qtB);
        if (t <= qtA)
            attn_strip(Ks, Vs, psw, aqA, mA, lA, OA, w, quad, l16, t == qtA);
    }

    // ---- normalize + write ctx in place over qw (own slices only) ----
#pragma unroll
    for (int half = 0; half < 2; ++half) {
        const int qt = half ? qtB : qtA;
        const float* lr = half ? lB : lA;
        const f32x4* O = half ? OB : OA;
        u16* og = qw + (size_t)(b * 1024 + qt * 64 + w * 16 + quad * 4) * 1024 + h * 64;
#pragma unroll
        for (int reg = 0; reg < 4; ++reg) {
            const float inv = 1.f / lr[reg];
#pragma unroll
            for (int j = 0; j < 4; ++j)
                og[(size_t)reg * 1024 + j * 16 + l16] = f2bf(O[j][reg] * inv);
        }
    }
}

// ---------------------------------------------------------------------------
extern "C" void kernel_launch(void* const* d_in, const int* in_sizes, int n_in,
                              void* d_out, int out_size, void* d_ws, size_t ws_size,
                              hipStream_t stream)
{
    const void* query = d_in[0];
    const void* key   = d_in[1];
    const void* value = d_in[2];
    // d_in[3] = mask: exactly tril(ones) -> causal, not read
    const void* Wq = d_in[4];
    const void* bq = d_in[5];
    const void* Wk = d_in[6];
    const void* bk = d_in[7];
    const void* Wv = d_in[8];
    const void* bv = d_in[9];
    const void* Wo = d_in[10];
    const void* bo = d_in[11];

    // ws (u16 units, M1 = 1Mi elems = 2MB): qw@0 kw@4 vw@8 wt_o@12
    // wt_q@13 wt_k@14 wt_v@15 | vt@13 (overlays wt_q..wt_v+1, written AFTER
    // the QKV GEMMs consume them) | flag@17.  Total 34MB+4 (<=38MB proven).
    constexpr size_t M1 = 1024 * 1024;
    u16* qw   = (u16*)d_ws;
    u16* kw   = qw + 4 * M1;
    u16* vw   = qw + 8 * M1;
    u16* wt_o = qw + 12 * M1;
    u16* wt_q = qw + 13 * M1;
    u16* wt_k = qw + 14 * M1;
    u16* wt_v = qw + 15 * M1;
    u16* vt   = qw + 13 * M1;     // overlays wt_q/k/v after they are dead
    int* flag = (int*)(qw + 17 * M1);

    sniff_kernel<<<1, 64, 0, stream>>>((const u16*)query, flag);

    T4 wT; wT.src[0] = Wq; wT.src[1] = Wk; wT.src[2] = Wv; wT.src[3] = Wo;
    wT.dst[0] = wt_q; wT.dst[1] = wt_k; wT.dst[2] = wt_v; wT.dst[3] = wt_o;
    transpose64<<<dim3(16, 16, 4), 256, 0, stream>>>(wT, flag, 1);

    G3 qkv;
    qkv.g[0] = G1{query, wt_q, bq, qw};
    qkv.g[1] = G1{key,   wt_k, bk, kw};
    qkv.g[2] = G1{value, wt_v, bv, vw};
    gemm_mfma<<<dim3(32, 8, 3), 256, 0, stream>>>(qkv, flag, 1, 0);

    T4 vT;
    for (int bb = 0; bb < 4; ++bb) { vT.src[bb] = vw + bb * M1; vT.dst[bb] = vt + bb * M1; }
    transpose64<<<dim3(16, 16, 4), 256, 0, stream>>>(vT, flag, 0);

    attn_mfma<<<dim3(8, 64), 256, 0, stream>>>(qw, kw, vt);

    G3 og; og.g[0] = G1{qw, wt_o, bo, d_out};
    gemm_mfma<<<dim3(32, 8, 1), 256, 0, stream>>>(og, flag, 0, 1);
}